// Round 3
// baseline (129.379 us; speedup 1.0000x reference)
//
#include <hip/hip_runtime.h>

typedef __bf16 bf16x4 __attribute__((ext_vector_type(4)));
typedef __bf16 bf16x8 __attribute__((ext_vector_type(8)));
typedef float  f32x4v __attribute__((ext_vector_type(4)));

#define HS 136   // padded row stride in bf16 halfwords (272 B, 16B-aligned)

// ---------------------------------------------------------------------------
// inputs fp32, output fp32. h[bn,i,j,f] = Up[bn,i,f]+V[bn,j,f]+delta_ij*Dg[bn,i,f]
//   Up = x_i.W1b + mean.W1e + b1 ; V = x_j.W1c ; Dg = x_i.W1a + mean.W1d
// out = relu(LN_f(h))(+delta_ij*bias_p) @ W2^T + b2
// K1 : split-bf16 MFMA (hi/lo, ~fp32-exact) -> Up/V/Dg fp32 ws + W2->bf16.
// K1b: LN stats precompute. For i!=j: sum h = SU_i+SV_j, sum h^2 =
//      PU_i+PV_j+2*Q_ij with Q = Up.V^T (split-bf16 MFMA). Diagonal rows
//      reduced directly in fp32. Stores Mu/Rs (f32 scalars per (i,j)).
// K2 (R9): no cross-lane LN at all. Each lane builds its MFMA B-fragment
//      values directly (row j=16w+m, cols 32ks+8quad+e) using the
//      precomputed mu/rstd. Hs buffer + 80 shfl/thread removed;
//      LDS 52.2->34.8 KB => 4 blocks/CU.
// ---------------------------------------------------------------------------

// K1: grid 192 = 32 bn x 6 chunks; chunk ch -> part pidx=ch>>1 (0=Dg,1=Up,2=V),
// f-tiles (4ch..4ch+3)&7 of that part.
__global__ __launch_bounds__(256) void k1_prep(
    const float* __restrict__ x, const float* __restrict__ W1,
    const float* __restrict__ b1, const float* __restrict__ W2,
    float* __restrict__ Up, float* __restrict__ V, float* __restrict__ Dg,
    __bf16* __restrict__ W2b)
{
  __shared__ __align__(16) __bf16 Xhi[64 * HS];
  __shared__ __align__(16) __bf16 Xlo[64 * HS];
  __shared__ float msum[128], pm[256], mw[128];

  const int tid  = threadIdx.x;
  const int bn   = blockIdx.x / 6;
  const int ch   = blockIdx.x % 6;
  const int lane = tid & 63;
  const int w    = tid >> 6;
  const int pidx = ch >> 1;

  if (tid < 128) msum[tid] = 0.f;
  __syncthreads();

  // stage x -> hi/lo bf16 LDS + fp32 column sums (atomic)
  {
    const float4* xv = reinterpret_cast<const float4*>(x + (size_t)bn * 8192);
    const int c = tid & 31;
    float4 ps = {0.f, 0.f, 0.f, 0.f};
#pragma unroll
    for (int it = 0; it < 8; ++it) {
      int p = tid + 256 * it;
      int r = p >> 5;
      float4 v = xv[p];
      ps.x += v.x; ps.y += v.y; ps.z += v.z; ps.w += v.w;
      bf16x4 hv, lv;
      hv[0] = (__bf16)v.x; lv[0] = (__bf16)(v.x - (float)hv[0]);
      hv[1] = (__bf16)v.y; lv[1] = (__bf16)(v.y - (float)hv[1]);
      hv[2] = (__bf16)v.z; lv[2] = (__bf16)(v.z - (float)hv[2]);
      hv[3] = (__bf16)v.w; lv[3] = (__bf16)(v.w - (float)hv[3]);
      *reinterpret_cast<bf16x4*>(&Xhi[r * HS + 4 * c]) = hv;
      *reinterpret_cast<bf16x4*>(&Xlo[r * HS + 4 * c]) = lv;
    }
    atomicAdd(&msum[4 * c + 0], ps.x);
    atomicAdd(&msum[4 * c + 1], ps.y);
    atomicAdd(&msum[4 * c + 2], ps.z);
    atomicAdd(&msum[4 * c + 3], ps.w);
  }

  // W2 fp32 -> bf16 ws (ch==4 blocks, identical writes: benign)
  if (ch == 4) {
    const float4* w2v = reinterpret_cast<const float4*>(W2);
#pragma unroll
    for (int it = 0; it < 16; ++it) {
      int p = tid + 256 * it;
      float4 v = w2v[p];
      bf16x4 hv;
      hv[0] = (__bf16)v.x; hv[1] = (__bf16)v.y;
      hv[2] = (__bf16)v.z; hv[3] = (__bf16)v.w;
      reinterpret_cast<bf16x4*>(W2b)[p] = hv;
    }
  }
  __syncthreads();

  // mean matvec (fp32): 2 threads per f, 64 MACs each; msum holds SUMS (x64)
  {
    const int f  = tid & 127;
    const int hh = tid >> 7;
    float acc = 0.f;
    if (pidx < 2) {
      const float4* wv4 = reinterpret_cast<const float4*>(
          W1 + (size_t)f * 640 + (pidx == 0 ? 384 : 512) + hh * 64);
#pragma unroll
      for (int kc = 0; kc < 16; ++kc) {
        float4 wv = wv4[kc];
        int k = hh * 64 + 4 * kc;
        acc += msum[k] * wv.x + msum[k + 1] * wv.y +
               msum[k + 2] * wv.z + msum[k + 3] * wv.w;
      }
    }
    pm[tid] = acc;
  }
  __syncthreads();
  if (tid < 128)
    mw[tid] = (pm[tid] + pm[tid + 128]) * (1.f / 64.f) +
              (pidx == 1 ? b1[tid] : 0.f);
  __syncthreads();

  // MFMA: wave w owns m-rows 16w..16w+15; 4 f-tiles x 4 ks x 3 (hi/lo) MFMAs
  const int m    = lane & 15;
  const int quad = lane >> 4;
  bf16x8 ahi[4], alo[4];
#pragma unroll
  for (int ks = 0; ks < 4; ++ks) {
    ahi[ks] = *reinterpret_cast<const bf16x8*>(&Xhi[(16 * w + m) * HS + 32 * ks + 8 * quad]);
    alo[ks] = *reinterpret_cast<const bf16x8*>(&Xlo[(16 * w + m) * HS + 32 * ks + 8 * quad]);
  }

  float* rout = (pidx == 0) ? Dg : (pidx == 1 ? Up : V);
#pragma unroll
  for (int tt = 0; tt < 4; ++tt) {
    const int fout = (((4 * ch + tt) & 7) * 16) + m;
    const float* wrow = W1 + (size_t)fout * 640 + pidx * 128;
    f32x4v a = {0.f, 0.f, 0.f, 0.f};
#pragma unroll
    for (int ks = 0; ks < 4; ++ks) {
      float4 w0 = *reinterpret_cast<const float4*>(wrow + 32 * ks + 8 * quad);
      float4 w1 = *reinterpret_cast<const float4*>(wrow + 32 * ks + 8 * quad + 4);
      bf16x8 bhi, blo;
      bhi[0] = (__bf16)w0.x; blo[0] = (__bf16)(w0.x - (float)bhi[0]);
      bhi[1] = (__bf16)w0.y; blo[1] = (__bf16)(w0.y - (float)bhi[1]);
      bhi[2] = (__bf16)w0.z; blo[2] = (__bf16)(w0.z - (float)bhi[2]);
      bhi[3] = (__bf16)w0.w; blo[3] = (__bf16)(w0.w - (float)bhi[3]);
      bhi[4] = (__bf16)w1.x; blo[4] = (__bf16)(w1.x - (float)bhi[4]);
      bhi[5] = (__bf16)w1.y; blo[5] = (__bf16)(w1.y - (float)bhi[5]);
      bhi[6] = (__bf16)w1.z; blo[6] = (__bf16)(w1.z - (float)bhi[6]);
      bhi[7] = (__bf16)w1.w; blo[7] = (__bf16)(w1.w - (float)bhi[7]);
      a = __builtin_amdgcn_mfma_f32_16x16x32_bf16(ahi[ks], bhi, a, 0, 0, 0);
      a = __builtin_amdgcn_mfma_f32_16x16x32_bf16(alo[ks], bhi, a, 0, 0, 0);
      a = __builtin_amdgcn_mfma_f32_16x16x32_bf16(ahi[ks], blo, a, 0, 0, 0);
    }
    const float addv = mw[fout];
#pragma unroll
    for (int rg = 0; rg < 4; ++rg) {
      int ii = 16 * w + 4 * quad + rg;
      rout[((size_t)bn * 64 + ii) * 128 + fout] = a[rg] + addv;
    }
  }
}

// K1b: grid 128 = 32 bn x 4 i-groups. Computes Mu/Rs for all (i,j).
// Q = Up.V^T via split-bf16 (3 MFMAs per k-slice, ~fp32-exact).
__global__ __launch_bounds__(256) void k1b_stats(
    const float* __restrict__ Up, const float* __restrict__ V,
    const float* __restrict__ Dg, float* __restrict__ Mu,
    float* __restrict__ Rs)
{
  __shared__ __align__(16) __bf16 Vhi[64 * HS];
  __shared__ __align__(16) __bf16 Vlo[64 * HS];
  __shared__ __align__(16) __bf16 Uhi[16 * HS];
  __shared__ __align__(16) __bf16 Ulo[16 * HS];
  __shared__ float SVs[64], PVs[64], SUs[16], PUs[16], dmus[16], drss[16];

  const int tid  = threadIdx.x;
  const int bn   = blockIdx.x >> 2;
  const int ig   = blockIdx.x & 3;
  const int lane = tid & 63;
  const int w    = tid >> 6;

  const float* Vb = V  + (size_t)bn * 8192;
  const float* Ub = Up + ((size_t)bn * 64 + 16 * ig) * 128;
  const float* Db = Dg + ((size_t)bn * 64 + 16 * ig) * 128;

  // stage V (all 64 rows) and Up (this block's 16 rows) as hi/lo bf16
  {
    const float4* vv = reinterpret_cast<const float4*>(Vb);
#pragma unroll
    for (int it = 0; it < 8; ++it) {
      int p = tid + 256 * it;
      int r = p >> 5, c = p & 31;
      float4 v = vv[p];
      bf16x4 hv, lv;
      hv[0] = (__bf16)v.x; lv[0] = (__bf16)(v.x - (float)hv[0]);
      hv[1] = (__bf16)v.y; lv[1] = (__bf16)(v.y - (float)hv[1]);
      hv[2] = (__bf16)v.z; lv[2] = (__bf16)(v.z - (float)hv[2]);
      hv[3] = (__bf16)v.w; lv[3] = (__bf16)(v.w - (float)hv[3]);
      *reinterpret_cast<bf16x4*>(&Vhi[r * HS + 4 * c]) = hv;
      *reinterpret_cast<bf16x4*>(&Vlo[r * HS + 4 * c]) = lv;
    }
    const float4* uv = reinterpret_cast<const float4*>(Ub);
#pragma unroll
    for (int it = 0; it < 2; ++it) {
      int p = tid + 256 * it;
      int r = p >> 5, c = p & 31;
      float4 v = uv[p];
      bf16x4 hv, lv;
      hv[0] = (__bf16)v.x; lv[0] = (__bf16)(v.x - (float)hv[0]);
      hv[1] = (__bf16)v.y; lv[1] = (__bf16)(v.y - (float)hv[1]);
      hv[2] = (__bf16)v.z; lv[2] = (__bf16)(v.z - (float)hv[2]);
      hv[3] = (__bf16)v.w; lv[3] = (__bf16)(v.w - (float)hv[3]);
      *reinterpret_cast<bf16x4*>(&Uhi[r * HS + 4 * c]) = hv;
      *reinterpret_cast<bf16x4*>(&Ulo[r * HS + 4 * c]) = lv;
    }
  }

  // per-row sums/sumsq (fp32, half-wave butterfly)
  {
    const int hw = tid >> 5;
    const int c  = tid & 31;
#pragma unroll
    for (int it = 0; it < 8; ++it) {
      int r = 8 * it + hw;
      float4 v = reinterpret_cast<const float4*>(Vb + (size_t)r * 128)[c];
      float s = v.x + v.y + v.z + v.w;
      float q = v.x * v.x + v.y * v.y + v.z * v.z + v.w * v.w;
#pragma unroll
      for (int off = 16; off > 0; off >>= 1) {
        s += __shfl_xor(s, off, 32);
        q += __shfl_xor(q, off, 32);
      }
      if (c == 0) { SVs[r] = s; PVs[r] = q; }
    }
#pragma unroll
    for (int it = 0; it < 2; ++it) {
      int r = 8 * it + hw;
      float4 u = reinterpret_cast<const float4*>(Ub + (size_t)r * 128)[c];
      float s = u.x + u.y + u.z + u.w;
      float q = u.x * u.x + u.y * u.y + u.z * u.z + u.w * u.w;
#pragma unroll
      for (int off = 16; off > 0; off >>= 1) {
        s += __shfl_xor(s, off, 32);
        q += __shfl_xor(q, off, 32);
      }
      if (c == 0) { SUs[r] = s; PUs[r] = q; }
    }
    // diagonal rows: h = Up + Dg + V, stats direct in fp32
#pragma unroll
    for (int it = 0; it < 2; ++it) {
      int r  = 8 * it + hw;
      int gi = 16 * ig + r;
      float4 u = reinterpret_cast<const float4*>(Ub + (size_t)r * 128)[c];
      float4 d = reinterpret_cast<const float4*>(Db + (size_t)r * 128)[c];
      float4 v = reinterpret_cast<const float4*>(Vb + (size_t)gi * 128)[c];
      float h0 = u.x + d.x + v.x, h1 = u.y + d.y + v.y;
      float h2 = u.z + d.z + v.z, h3 = u.w + d.w + v.w;
      float s = h0 + h1 + h2 + h3;
      float q = h0 * h0 + h1 * h1 + h2 * h2 + h3 * h3;
#pragma unroll
      for (int off = 16; off > 0; off >>= 1) {
        s += __shfl_xor(s, off, 32);
        q += __shfl_xor(q, off, 32);
      }
      if (c == 0) {
        float mu  = s * (1.f / 128.f);
        float var = q * (1.f / 128.f) - mu * mu;
        dmus[r] = mu;
        drss[r] = rsqrtf(var + 1e-5f);
      }
    }
  }
  __syncthreads();

  // Q tile: wave w = j-tile; A = V rows 16w+m, B = Up local rows m.
  // D[4*quad+rg -> j within tile, m -> i local] (same verified mapping as K2).
  const int m    = lane & 15;
  const int quad = lane >> 4;
  f32x4v a = {0.f, 0.f, 0.f, 0.f};
#pragma unroll
  for (int ks = 0; ks < 4; ++ks) {
    bf16x8 vah = *reinterpret_cast<const bf16x8*>(&Vhi[(16 * w + m) * HS + 32 * ks + 8 * quad]);
    bf16x8 val = *reinterpret_cast<const bf16x8*>(&Vlo[(16 * w + m) * HS + 32 * ks + 8 * quad]);
    bf16x8 ubh = *reinterpret_cast<const bf16x8*>(&Uhi[m * HS + 32 * ks + 8 * quad]);
    bf16x8 ubl = *reinterpret_cast<const bf16x8*>(&Ulo[m * HS + 32 * ks + 8 * quad]);
    a = __builtin_amdgcn_mfma_f32_16x16x32_bf16(vah, ubh, a, 0, 0, 0);
    a = __builtin_amdgcn_mfma_f32_16x16x32_bf16(val, ubh, a, 0, 0, 0);
    a = __builtin_amdgcn_mfma_f32_16x16x32_bf16(vah, ubl, a, 0, 0, 0);
  }

  const int i  = 16 * ig + m;
  const float su = SUs[m], pu = PUs[m];
  float* mrow = Mu + ((size_t)bn * 64 + i) * 64;
  float* rrow = Rs + ((size_t)bn * 64 + i) * 64;
#pragma unroll
  for (int rg = 0; rg < 4; ++rg) {
    int j = 16 * w + 4 * quad + rg;
    float mu  = (su + SVs[j]) * (1.f / 128.f);
    float q   = pu + PVs[j] + 2.f * a[rg];
    float var = q * (1.f / 128.f) - mu * mu;
    float rstd = rsqrtf(var + 1e-5f);
    if (w == ig && (4 * quad + rg) == m) { mu = dmus[m]; rstd = drss[m]; }
    mrow[j] = mu;
    rrow[j] = rstd;
  }
}

// K2 (R9): grid 2048 = (bn, i). LDS only W2s = 34.8 KB -> 4 blocks/CU.
// Each lane owns B-frag row j=16w+m; h-values built directly at frag cols
// (32ks+8quad+e) with precomputed mu/rstd -> no shfl, no Hs, one barrier.
__global__ __launch_bounds__(256) void k2_main(
    const float* __restrict__ Up, const float* __restrict__ V,
    const float* __restrict__ Dg, const __bf16* __restrict__ W2b,
    const float* __restrict__ Mu, const float* __restrict__ Rs,
    const float* __restrict__ gamma, const float* __restrict__ beta,
    const float* __restrict__ bias_p, const float* __restrict__ b2,
    float* __restrict__ out)
{
  __shared__ __align__(16) __bf16 W2s[128 * HS];

  const int tid  = threadIdx.x;
  const int bid  = blockIdx.x;
  const int bn   = bid >> 6;
  const int i    = bid & 63;
  const int lane = tid & 63;
  const int w    = tid >> 6;
  const int m    = lane & 15;
  const int quad = lane >> 4;

  // stage W2 bf16 into padded LDS (latency hides under h-frag build)
  {
    const uint4* w2v = reinterpret_cast<const uint4*>(W2b);
#pragma unroll
    for (int it = 0; it < 8; ++it) {
      int p   = tid + 256 * it;
      int row = p >> 4;
      int col = (p & 15) * 8;
      *reinterpret_cast<uint4*>(&W2s[row * HS + col]) = w2v[p];
    }
  }

  // build B-fragments directly: row j = 16w+m, cols 32ks+8quad+(0..7)
  const int j = 16 * w + m;
  const size_t base = (size_t)bn * 64;
  const float mu = Mu[(base + i) * 64 + j];
  const float rs = Rs[(base + i) * 64 + j];
  const bool  dia = (j == i);
  const float* uprow = Up + (base + i) * 128;
  const float* vrow  = V  + (base + j) * 128;
  const float* dgrow = Dg + (base + i) * 128;

  bf16x8 hfrag[4];
#pragma unroll
  for (int ks = 0; ks < 4; ++ks) {
    const int c0 = 32 * ks + 8 * quad;
    float4 u0 = *reinterpret_cast<const float4*>(uprow + c0);
    float4 u1 = *reinterpret_cast<const float4*>(uprow + c0 + 4);
    float4 v0 = *reinterpret_cast<const float4*>(vrow + c0);
    float4 v1 = *reinterpret_cast<const float4*>(vrow + c0 + 4);
    float h[8] = {u0.x + v0.x, u0.y + v0.y, u0.z + v0.z, u0.w + v0.w,
                  u1.x + v1.x, u1.y + v1.y, u1.z + v1.z, u1.w + v1.w};
    if (dia) {
      float4 d0 = *reinterpret_cast<const float4*>(dgrow + c0);
      float4 d1 = *reinterpret_cast<const float4*>(dgrow + c0 + 4);
      h[0] += d0.x; h[1] += d0.y; h[2] += d0.z; h[3] += d0.w;
      h[4] += d1.x; h[5] += d1.y; h[6] += d1.z; h[7] += d1.w;
    }
    float4 g0  = *reinterpret_cast<const float4*>(gamma + c0);
    float4 g1  = *reinterpret_cast<const float4*>(gamma + c0 + 4);
    float4 be0 = *reinterpret_cast<const float4*>(beta + c0);
    float4 be1 = *reinterpret_cast<const float4*>(beta + c0 + 4);
    float gg[8] = {g0.x, g0.y, g0.z, g0.w, g1.x, g1.y, g1.z, g1.w};
    float bb[8] = {be0.x, be0.y, be0.z, be0.w, be1.x, be1.y, be1.z, be1.w};
    float r8[8];
#pragma unroll
    for (int e = 0; e < 8; ++e)
      r8[e] = fmaxf(fmaf((h[e] - mu) * rs, gg[e], bb[e]), 0.f);
    if (dia) {
      float4 bp0 = *reinterpret_cast<const float4*>(bias_p + c0);
      float4 bp1 = *reinterpret_cast<const float4*>(bias_p + c0 + 4);
      r8[0] += bp0.x; r8[1] += bp0.y; r8[2] += bp0.z; r8[3] += bp0.w;
      r8[4] += bp1.x; r8[5] += bp1.y; r8[6] += bp1.z; r8[7] += bp1.w;
    }
    bf16x8 f;
#pragma unroll
    for (int e = 0; e < 8; ++e) f[e] = (__bf16)r8[e];
    hfrag[ks] = f;
  }
  __syncthreads();

  // MFMA: A = W2s row d=16t+m (LDS), B = hfrag (registers).
  // D[4*quad+rg -> d, m -> j]; rg contiguous in d => float4 stores.
  const size_t obase = (size_t)bid * 8192;
  float* orow = out + obase + (size_t)j * 128;
#pragma unroll
  for (int t = 0; t < 8; ++t) {
    f32x4v a = {0.f, 0.f, 0.f, 0.f};
#pragma unroll
    for (int ks = 0; ks < 4; ++ks) {
      bf16x8 aw = *reinterpret_cast<const bf16x8*>(
          &W2s[(16 * t + m) * HS + 32 * ks + 8 * quad]);
      a = __builtin_amdgcn_mfma_f32_16x16x32_bf16(aw, hfrag[ks], a, 0, 0, 0);
    }
    const float4 b2v = *reinterpret_cast<const float4*>(b2 + 16 * t + 4 * quad);
    float4 o;
    o.x = a[0] + b2v.x; o.y = a[1] + b2v.y;
    o.z = a[2] + b2v.z; o.w = a[3] + b2v.w;
    *reinterpret_cast<float4*>(orow + 16 * t + 4 * quad) = o;
  }
}

extern "C" void kernel_launch(void* const* d_in, const int* in_sizes, int n_in,
                              void* d_out, int out_size, void* d_ws, size_t ws_size,
                              hipStream_t stream) {
  const float* x      = (const float*)d_in[0];
  const float* W1     = (const float*)d_in[1];
  const float* b1     = (const float*)d_in[2];
  const float* gamma  = (const float*)d_in[3];
  const float* beta   = (const float*)d_in[4];
  const float* bias_p = (const float*)d_in[5];
  const float* W2     = (const float*)d_in[6];
  const float* b2     = (const float*)d_in[7];

  float*  Up  = (float*)d_ws;
  float*  V   = Up + 2048 * 128;
  float*  Dg  = V + 2048 * 128;
  __bf16* W2b = (__bf16*)(Dg + 2048 * 128);
  float*  Mu  = (float*)(W2b + 16384);
  float*  Rs  = Mu + 2048 * 64;

  k1_prep<<<192, 256, 0, stream>>>(x, W1, b1, W2, Up, V, Dg, W2b);
  k1b_stats<<<128, 256, 0, stream>>>(Up, V, Dg, Mu, Rs);
  k2_main<<<2048, 256, 0, stream>>>(Up, V, Dg, W2b, Mu, Rs, gamma, beta,
                                    bias_p, b2, (float*)d_out);
}

// Round 4
// 119.749 us; speedup vs baseline: 1.0804x; 1.0804x over previous
//
#include <hip/hip_runtime.h>

typedef __bf16 bf16x4 __attribute__((ext_vector_type(4)));
typedef __bf16 bf16x8 __attribute__((ext_vector_type(8)));
typedef float  f32x4v __attribute__((ext_vector_type(4)));

#define HS 136   // padded row stride in bf16 halfwords (272 B, 16B-aligned)

// ---------------------------------------------------------------------------
// inputs fp32, output fp32. h[bn,i,j,f] = Up[bn,i,f]+V[bn,j,f]+delta_ij*Dg[bn,i,f]
//   Up = x_i.W1b + mean.W1e + b1 ; V = x_j.W1c ; Dg = x_i.W1a + mean.W1d
// out = relu(LN_f(h))(+delta_ij*bias_p) @ W2^T + b2
// K1 : split-bf16 MFMA (hi/lo, ~fp32-exact) -> Up/V/Dg fp32 ws + W2->bf16.
// K2 (R10): each lane owns B-frag row j=16w+m and builds its 32 h-values
//   directly at frag cols (32ks+8quad+e). The 4 quad-lanes of an m cover all
//   128 cols of row j => LN stats via 2x shfl_xor (16,32). No Hs buffer, no
//   stats kernel, one barrier. LDS = W2s only (34.8 KB) -> 4 blocks/CU.
//   (R9 lesson: extra launch + global Mu/Rs round-trip cost ~15 us; in-kernel
//    4-shfl reduce is nearly free.)
// ---------------------------------------------------------------------------

// K1: grid 192 = 32 bn x 6 chunks; chunk ch -> part pidx=ch>>1 (0=Dg,1=Up,2=V),
// f-tiles (4ch..4ch+3)&7 of that part.
__global__ __launch_bounds__(256) void k1_prep(
    const float* __restrict__ x, const float* __restrict__ W1,
    const float* __restrict__ b1, const float* __restrict__ W2,
    float* __restrict__ Up, float* __restrict__ V, float* __restrict__ Dg,
    __bf16* __restrict__ W2b)
{
  __shared__ __align__(16) __bf16 Xhi[64 * HS];
  __shared__ __align__(16) __bf16 Xlo[64 * HS];
  __shared__ float msum[128], pm[256], mw[128];

  const int tid  = threadIdx.x;
  const int bn   = blockIdx.x / 6;
  const int ch   = blockIdx.x % 6;
  const int lane = tid & 63;
  const int w    = tid >> 6;
  const int pidx = ch >> 1;

  if (tid < 128) msum[tid] = 0.f;
  __syncthreads();

  // stage x -> hi/lo bf16 LDS + fp32 column sums (atomic)
  {
    const float4* xv = reinterpret_cast<const float4*>(x + (size_t)bn * 8192);
    const int c = tid & 31;
    float4 ps = {0.f, 0.f, 0.f, 0.f};
#pragma unroll
    for (int it = 0; it < 8; ++it) {
      int p = tid + 256 * it;
      int r = p >> 5;
      float4 v = xv[p];
      ps.x += v.x; ps.y += v.y; ps.z += v.z; ps.w += v.w;
      bf16x4 hv, lv;
      hv[0] = (__bf16)v.x; lv[0] = (__bf16)(v.x - (float)hv[0]);
      hv[1] = (__bf16)v.y; lv[1] = (__bf16)(v.y - (float)hv[1]);
      hv[2] = (__bf16)v.z; lv[2] = (__bf16)(v.z - (float)hv[2]);
      hv[3] = (__bf16)v.w; lv[3] = (__bf16)(v.w - (float)hv[3]);
      *reinterpret_cast<bf16x4*>(&Xhi[r * HS + 4 * c]) = hv;
      *reinterpret_cast<bf16x4*>(&Xlo[r * HS + 4 * c]) = lv;
    }
    atomicAdd(&msum[4 * c + 0], ps.x);
    atomicAdd(&msum[4 * c + 1], ps.y);
    atomicAdd(&msum[4 * c + 2], ps.z);
    atomicAdd(&msum[4 * c + 3], ps.w);
  }

  // W2 fp32 -> bf16 ws (ch==4 blocks, identical writes: benign)
  if (ch == 4) {
    const float4* w2v = reinterpret_cast<const float4*>(W2);
#pragma unroll
    for (int it = 0; it < 16; ++it) {
      int p = tid + 256 * it;
      float4 v = w2v[p];
      bf16x4 hv;
      hv[0] = (__bf16)v.x; hv[1] = (__bf16)v.y;
      hv[2] = (__bf16)v.z; hv[3] = (__bf16)v.w;
      reinterpret_cast<bf16x4*>(W2b)[p] = hv;
    }
  }
  __syncthreads();

  // mean matvec (fp32): 2 threads per f, 64 MACs each; msum holds SUMS (x64)
  {
    const int f  = tid & 127;
    const int hh = tid >> 7;
    float acc = 0.f;
    if (pidx < 2) {
      const float4* wv4 = reinterpret_cast<const float4*>(
          W1 + (size_t)f * 640 + (pidx == 0 ? 384 : 512) + hh * 64);
#pragma unroll
      for (int kc = 0; kc < 16; ++kc) {
        float4 wv = wv4[kc];
        int k = hh * 64 + 4 * kc;
        acc += msum[k] * wv.x + msum[k + 1] * wv.y +
               msum[k + 2] * wv.z + msum[k + 3] * wv.w;
      }
    }
    pm[tid] = acc;
  }
  __syncthreads();
  if (tid < 128)
    mw[tid] = (pm[tid] + pm[tid + 128]) * (1.f / 64.f) +
              (pidx == 1 ? b1[tid] : 0.f);
  __syncthreads();

  // MFMA: wave w owns m-rows 16w..16w+15; 4 f-tiles x 4 ks x 3 (hi/lo) MFMAs
  const int m    = lane & 15;
  const int quad = lane >> 4;
  bf16x8 ahi[4], alo[4];
#pragma unroll
  for (int ks = 0; ks < 4; ++ks) {
    ahi[ks] = *reinterpret_cast<const bf16x8*>(&Xhi[(16 * w + m) * HS + 32 * ks + 8 * quad]);
    alo[ks] = *reinterpret_cast<const bf16x8*>(&Xlo[(16 * w + m) * HS + 32 * ks + 8 * quad]);
  }

  float* rout = (pidx == 0) ? Dg : (pidx == 1 ? Up : V);
#pragma unroll
  for (int tt = 0; tt < 4; ++tt) {
    const int fout = (((4 * ch + tt) & 7) * 16) + m;
    const float* wrow = W1 + (size_t)fout * 640 + pidx * 128;
    f32x4v a = {0.f, 0.f, 0.f, 0.f};
#pragma unroll
    for (int ks = 0; ks < 4; ++ks) {
      float4 w0 = *reinterpret_cast<const float4*>(wrow + 32 * ks + 8 * quad);
      float4 w1 = *reinterpret_cast<const float4*>(wrow + 32 * ks + 8 * quad + 4);
      bf16x8 bhi, blo;
      bhi[0] = (__bf16)w0.x; blo[0] = (__bf16)(w0.x - (float)bhi[0]);
      bhi[1] = (__bf16)w0.y; blo[1] = (__bf16)(w0.y - (float)bhi[1]);
      bhi[2] = (__bf16)w0.z; blo[2] = (__bf16)(w0.z - (float)bhi[2]);
      bhi[3] = (__bf16)w0.w; blo[3] = (__bf16)(w0.w - (float)bhi[3]);
      bhi[4] = (__bf16)w1.x; blo[4] = (__bf16)(w1.x - (float)bhi[4]);
      bhi[5] = (__bf16)w1.y; blo[5] = (__bf16)(w1.y - (float)bhi[5]);
      bhi[6] = (__bf16)w1.z; blo[6] = (__bf16)(w1.z - (float)bhi[6]);
      bhi[7] = (__bf16)w1.w; blo[7] = (__bf16)(w1.w - (float)bhi[7]);
      a = __builtin_amdgcn_mfma_f32_16x16x32_bf16(ahi[ks], bhi, a, 0, 0, 0);
      a = __builtin_amdgcn_mfma_f32_16x16x32_bf16(alo[ks], bhi, a, 0, 0, 0);
      a = __builtin_amdgcn_mfma_f32_16x16x32_bf16(ahi[ks], blo, a, 0, 0, 0);
    }
    const float addv = mw[fout];
#pragma unroll
    for (int rg = 0; rg < 4; ++rg) {
      int ii = 16 * w + 4 * quad + rg;
      rout[((size_t)bn * 64 + ii) * 128 + fout] = a[rg] + addv;
    }
  }
}

// K2 (R10): grid 2048 = (bn, i). LDS only W2s = 34.8 KB -> 4 blocks/CU.
// Lane owns row j=16w+m; h built at frag cols; LN stats via quad-reduce
// (shfl_xor 16, 32 — lanes {m,m+16,m+32,m+48} cover all 128 cols).
__global__ __launch_bounds__(256) void k2_main(
    const float* __restrict__ Up, const float* __restrict__ V,
    const float* __restrict__ Dg, const __bf16* __restrict__ W2b,
    const float* __restrict__ gamma, const float* __restrict__ beta,
    const float* __restrict__ bias_p, const float* __restrict__ b2,
    float* __restrict__ out)
{
  __shared__ __align__(16) __bf16 W2s[128 * HS];

  const int tid  = threadIdx.x;
  const int bid  = blockIdx.x;
  const int bn   = bid >> 6;
  const int i    = bid & 63;
  const int lane = tid & 63;
  const int w    = tid >> 6;
  const int m    = lane & 15;
  const int quad = lane >> 4;

  // stage W2 bf16 into padded LDS (latency hides under h-build below)
  {
    const uint4* w2v = reinterpret_cast<const uint4*>(W2b);
#pragma unroll
    for (int it = 0; it < 8; ++it) {
      int p   = tid + 256 * it;
      int row = p >> 4;
      int col = (p & 15) * 8;
      *reinterpret_cast<uint4*>(&W2s[row * HS + col]) = w2v[p];
    }
  }

  // build h (32 fp32 per lane) at frag cols, accumulate partial stats
  const int j = 16 * w + m;
  const size_t base = (size_t)bn * 64;
  const bool  dia = (j == i);
  const float* uprow = Up + (base + i) * 128;
  const float* vrow  = V  + (base + j) * 128;
  const float* dgrow = Dg + (base + i) * 128;

  float h[4][8];
  float s = 0.f, q = 0.f;
#pragma unroll
  for (int ks = 0; ks < 4; ++ks) {
    const int c0 = 32 * ks + 8 * quad;
    float4 u0 = *reinterpret_cast<const float4*>(uprow + c0);
    float4 u1 = *reinterpret_cast<const float4*>(uprow + c0 + 4);
    float4 v0 = *reinterpret_cast<const float4*>(vrow + c0);
    float4 v1 = *reinterpret_cast<const float4*>(vrow + c0 + 4);
    h[ks][0] = u0.x + v0.x; h[ks][1] = u0.y + v0.y;
    h[ks][2] = u0.z + v0.z; h[ks][3] = u0.w + v0.w;
    h[ks][4] = u1.x + v1.x; h[ks][5] = u1.y + v1.y;
    h[ks][6] = u1.z + v1.z; h[ks][7] = u1.w + v1.w;
    if (dia) {
      float4 d0 = *reinterpret_cast<const float4*>(dgrow + c0);
      float4 d1 = *reinterpret_cast<const float4*>(dgrow + c0 + 4);
      h[ks][0] += d0.x; h[ks][1] += d0.y; h[ks][2] += d0.z; h[ks][3] += d0.w;
      h[ks][4] += d1.x; h[ks][5] += d1.y; h[ks][6] += d1.z; h[ks][7] += d1.w;
    }
#pragma unroll
    for (int e = 0; e < 8; ++e) {
      s += h[ks][e];
      q += h[ks][e] * h[ks][e];
    }
  }
  // quad-reduce: lanes {m, m+16, m+32, m+48} together hold the full row
  s += __shfl_xor(s, 16, 64);
  s += __shfl_xor(s, 32, 64);
  q += __shfl_xor(q, 16, 64);
  q += __shfl_xor(q, 32, 64);
  const float mu   = s * (1.f / 128.f);
  const float var  = q * (1.f / 128.f) - mu * mu;
  const float rstd = rsqrtf(var + 1e-5f);

  // normalize -> bf16 B-fragments
  bf16x8 hfrag[4];
#pragma unroll
  for (int ks = 0; ks < 4; ++ks) {
    const int c0 = 32 * ks + 8 * quad;
    float4 g0  = *reinterpret_cast<const float4*>(gamma + c0);
    float4 g1  = *reinterpret_cast<const float4*>(gamma + c0 + 4);
    float4 be0 = *reinterpret_cast<const float4*>(beta + c0);
    float4 be1 = *reinterpret_cast<const float4*>(beta + c0 + 4);
    float gg[8] = {g0.x, g0.y, g0.z, g0.w, g1.x, g1.y, g1.z, g1.w};
    float bb[8] = {be0.x, be0.y, be0.z, be0.w, be1.x, be1.y, be1.z, be1.w};
    float r8[8];
#pragma unroll
    for (int e = 0; e < 8; ++e)
      r8[e] = fmaxf(fmaf((h[ks][e] - mu) * rstd, gg[e], bb[e]), 0.f);
    if (dia) {
      float4 bp0 = *reinterpret_cast<const float4*>(bias_p + c0);
      float4 bp1 = *reinterpret_cast<const float4*>(bias_p + c0 + 4);
      r8[0] += bp0.x; r8[1] += bp0.y; r8[2] += bp0.z; r8[3] += bp0.w;
      r8[4] += bp1.x; r8[5] += bp1.y; r8[6] += bp1.z; r8[7] += bp1.w;
    }
    bf16x8 f;
#pragma unroll
    for (int e = 0; e < 8; ++e) f[e] = (__bf16)r8[e];
    hfrag[ks] = f;
  }
  __syncthreads();

  // MFMA: A = W2s row d=16t+m (LDS), B = hfrag (registers).
  // D[4*quad+rg -> d, m -> j]; rg contiguous in d => float4 stores.
  const size_t obase = (size_t)bid * 8192;
  float* orow = out + obase + (size_t)j * 128;
#pragma unroll
  for (int t = 0; t < 8; ++t) {
    f32x4v a = {0.f, 0.f, 0.f, 0.f};
#pragma unroll
    for (int ks = 0; ks < 4; ++ks) {
      bf16x8 aw = *reinterpret_cast<const bf16x8*>(
          &W2s[(16 * t + m) * HS + 32 * ks + 8 * quad]);
      a = __builtin_amdgcn_mfma_f32_16x16x32_bf16(aw, hfrag[ks], a, 0, 0, 0);
    }
    const float4 b2v = *reinterpret_cast<const float4*>(b2 + 16 * t + 4 * quad);
    float4 o;
    o.x = a[0] + b2v.x; o.y = a[1] + b2v.y;
    o.z = a[2] + b2v.z; o.w = a[3] + b2v.w;
    *reinterpret_cast<float4*>(orow + 16 * t + 4 * quad) = o;
  }
}

extern "C" void kernel_launch(void* const* d_in, const int* in_sizes, int n_in,
                              void* d_out, int out_size, void* d_ws, size_t ws_size,
                              hipStream_t stream) {
  const float* x      = (const float*)d_in[0];
  const float* W1     = (const float*)d_in[1];
  const float* b1     = (const float*)d_in[2];
  const float* gamma  = (const float*)d_in[3];
  const float* beta   = (const float*)d_in[4];
  const float* bias_p = (const float*)d_in[5];
  const float* W2     = (const float*)d_in[6];
  const float* b2     = (const float*)d_in[7];

  float*  Up  = (float*)d_ws;
  float*  V   = Up + 2048 * 128;
  float*  Dg  = V + 2048 * 128;
  __bf16* W2b = (__bf16*)(Dg + 2048 * 128);

  k1_prep<<<192, 256, 0, stream>>>(x, W1, b1, W2, Up, V, Dg, W2b);
  k2_main<<<2048, 256, 0, stream>>>(Up, V, Dg, W2b, gamma, beta, bias_p, b2,
                                    (float*)d_out);
}

// Round 5
// 117.984 us; speedup vs baseline: 1.0966x; 1.0150x over previous
//
#include <hip/hip_runtime.h>

typedef __bf16 bf16x4 __attribute__((ext_vector_type(4)));
typedef __bf16 bf16x8 __attribute__((ext_vector_type(8)));
typedef float  f32x4v __attribute__((ext_vector_type(4)));

#define HS 136   // padded row stride in bf16 halfwords (272 B, 16B-aligned)

// ---------------------------------------------------------------------------
// inputs fp32, output fp32. h[bn,i,j,f] = Up[bn,i,f]+V[bn,j,f]+delta_ij*Dg[bn,i,f]
//   Up = x_i.W1b + mean.W1e + b1 ; V = x_j.W1c ; Dg = x_i.W1a + mean.W1d
// out = relu(LN_f(h))(+delta_ij*bias_p) @ W2^T + b2
// K1 : split-bf16 MFMA (hi/lo, ~fp32-exact) -> Up/V/Dg fp32 ws + W2->bf16.
// K2 (R11): TWO i-rows per block (grid 1024 = 32bn x 32 pairs) to amortize
//   the per-block fixed costs (32KB W2 staging, V-frag loads, W2s ds_reads)
//   over 2x the output. Lane owns B-frag row j=16w+m, builds h at frag cols
//   (32ks+8quad+e); LN stats via 2x shfl_xor(16,32) quad-reduce (lanes
//   {m,m+16,m+32,m+48} cover all 128 cols). LDS = W2s only -> 4 blocks/CU,
//   whole grid co-resident.
// ---------------------------------------------------------------------------

// K1: grid 192 = 32 bn x 6 chunks; chunk ch -> part pidx=ch>>1 (0=Dg,1=Up,2=V),
// f-tiles (4ch..4ch+3)&7 of that part.
__global__ __launch_bounds__(256) void k1_prep(
    const float* __restrict__ x, const float* __restrict__ W1,
    const float* __restrict__ b1, const float* __restrict__ W2,
    float* __restrict__ Up, float* __restrict__ V, float* __restrict__ Dg,
    __bf16* __restrict__ W2b)
{
  __shared__ __align__(16) __bf16 Xhi[64 * HS];
  __shared__ __align__(16) __bf16 Xlo[64 * HS];
  __shared__ float msum[128], pm[256], mw[128];

  const int tid  = threadIdx.x;
  const int bn   = blockIdx.x / 6;
  const int ch   = blockIdx.x % 6;
  const int lane = tid & 63;
  const int w    = tid >> 6;
  const int pidx = ch >> 1;

  if (tid < 128) msum[tid] = 0.f;
  __syncthreads();

  // stage x -> hi/lo bf16 LDS + fp32 column sums (atomic)
  {
    const float4* xv = reinterpret_cast<const float4*>(x + (size_t)bn * 8192);
    const int c = tid & 31;
    float4 ps = {0.f, 0.f, 0.f, 0.f};
#pragma unroll
    for (int it = 0; it < 8; ++it) {
      int p = tid + 256 * it;
      int r = p >> 5;
      float4 v = xv[p];
      ps.x += v.x; ps.y += v.y; ps.z += v.z; ps.w += v.w;
      bf16x4 hv, lv;
      hv[0] = (__bf16)v.x; lv[0] = (__bf16)(v.x - (float)hv[0]);
      hv[1] = (__bf16)v.y; lv[1] = (__bf16)(v.y - (float)hv[1]);
      hv[2] = (__bf16)v.z; lv[2] = (__bf16)(v.z - (float)hv[2]);
      hv[3] = (__bf16)v.w; lv[3] = (__bf16)(v.w - (float)hv[3]);
      *reinterpret_cast<bf16x4*>(&Xhi[r * HS + 4 * c]) = hv;
      *reinterpret_cast<bf16x4*>(&Xlo[r * HS + 4 * c]) = lv;
    }
    atomicAdd(&msum[4 * c + 0], ps.x);
    atomicAdd(&msum[4 * c + 1], ps.y);
    atomicAdd(&msum[4 * c + 2], ps.z);
    atomicAdd(&msum[4 * c + 3], ps.w);
  }

  // W2 fp32 -> bf16 ws (ch==4 blocks, identical writes: benign)
  if (ch == 4) {
    const float4* w2v = reinterpret_cast<const float4*>(W2);
#pragma unroll
    for (int it = 0; it < 16; ++it) {
      int p = tid + 256 * it;
      float4 v = w2v[p];
      bf16x4 hv;
      hv[0] = (__bf16)v.x; hv[1] = (__bf16)v.y;
      hv[2] = (__bf16)v.z; hv[3] = (__bf16)v.w;
      reinterpret_cast<bf16x4*>(W2b)[p] = hv;
    }
  }
  __syncthreads();

  // mean matvec (fp32): 2 threads per f, 64 MACs each; msum holds SUMS (x64)
  {
    const int f  = tid & 127;
    const int hh = tid >> 7;
    float acc = 0.f;
    if (pidx < 2) {
      const float4* wv4 = reinterpret_cast<const float4*>(
          W1 + (size_t)f * 640 + (pidx == 0 ? 384 : 512) + hh * 64);
#pragma unroll
      for (int kc = 0; kc < 16; ++kc) {
        float4 wv = wv4[kc];
        int k = hh * 64 + 4 * kc;
        acc += msum[k] * wv.x + msum[k + 1] * wv.y +
               msum[k + 2] * wv.z + msum[k + 3] * wv.w;
      }
    }
    pm[tid] = acc;
  }
  __syncthreads();
  if (tid < 128)
    mw[tid] = (pm[tid] + pm[tid + 128]) * (1.f / 64.f) +
              (pidx == 1 ? b1[tid] : 0.f);
  __syncthreads();

  // MFMA: wave w owns m-rows 16w..16w+15; 4 f-tiles x 4 ks x 3 (hi/lo) MFMAs
  const int m    = lane & 15;
  const int quad = lane >> 4;
  bf16x8 ahi[4], alo[4];
#pragma unroll
  for (int ks = 0; ks < 4; ++ks) {
    ahi[ks] = *reinterpret_cast<const bf16x8*>(&Xhi[(16 * w + m) * HS + 32 * ks + 8 * quad]);
    alo[ks] = *reinterpret_cast<const bf16x8*>(&Xlo[(16 * w + m) * HS + 32 * ks + 8 * quad]);
  }

  float* rout = (pidx == 0) ? Dg : (pidx == 1 ? Up : V);
#pragma unroll
  for (int tt = 0; tt < 4; ++tt) {
    const int fout = (((4 * ch + tt) & 7) * 16) + m;
    const float* wrow = W1 + (size_t)fout * 640 + pidx * 128;
    f32x4v a = {0.f, 0.f, 0.f, 0.f};
#pragma unroll
    for (int ks = 0; ks < 4; ++ks) {
      float4 w0 = *reinterpret_cast<const float4*>(wrow + 32 * ks + 8 * quad);
      float4 w1 = *reinterpret_cast<const float4*>(wrow + 32 * ks + 8 * quad + 4);
      bf16x8 bhi, blo;
      bhi[0] = (__bf16)w0.x; blo[0] = (__bf16)(w0.x - (float)bhi[0]);
      bhi[1] = (__bf16)w0.y; blo[1] = (__bf16)(w0.y - (float)bhi[1]);
      bhi[2] = (__bf16)w0.z; blo[2] = (__bf16)(w0.z - (float)bhi[2]);
      bhi[3] = (__bf16)w0.w; blo[3] = (__bf16)(w0.w - (float)bhi[3]);
      bhi[4] = (__bf16)w1.x; blo[4] = (__bf16)(w1.x - (float)bhi[4]);
      bhi[5] = (__bf16)w1.y; blo[5] = (__bf16)(w1.y - (float)bhi[5]);
      bhi[6] = (__bf16)w1.z; blo[6] = (__bf16)(w1.z - (float)bhi[6]);
      bhi[7] = (__bf16)w1.w; blo[7] = (__bf16)(w1.w - (float)bhi[7]);
      a = __builtin_amdgcn_mfma_f32_16x16x32_bf16(ahi[ks], bhi, a, 0, 0, 0);
      a = __builtin_amdgcn_mfma_f32_16x16x32_bf16(alo[ks], bhi, a, 0, 0, 0);
      a = __builtin_amdgcn_mfma_f32_16x16x32_bf16(ahi[ks], blo, a, 0, 0, 0);
    }
    const float addv = mw[fout];
#pragma unroll
    for (int rg = 0; rg < 4; ++rg) {
      int ii = 16 * w + 4 * quad + rg;
      rout[((size_t)bn * 64 + ii) * 128 + fout] = a[rg] + addv;
    }
  }
}

// K2 (R11): grid 1024 = 32 bn x 32 i-pairs. LDS only W2s = 34.8 KB.
__global__ __launch_bounds__(256) void k2_main(
    const float* __restrict__ Up, const float* __restrict__ V,
    const float* __restrict__ Dg, const __bf16* __restrict__ W2b,
    const float* __restrict__ gamma, const float* __restrict__ beta,
    const float* __restrict__ bias_p, const float* __restrict__ b2,
    float* __restrict__ out)
{
  __shared__ __align__(16) __bf16 W2s[128 * HS];

  const int tid  = threadIdx.x;
  const int bid  = blockIdx.x;
  const int bn   = bid >> 5;
  const int ig   = bid & 31;
  const int i0   = 2 * ig;
  const int lane = tid & 63;
  const int w    = tid >> 6;
  const int m    = lane & 15;
  const int quad = lane >> 4;

  // stage W2 bf16 into padded LDS (latency hides under h-build below)
  {
    const uint4* w2v = reinterpret_cast<const uint4*>(W2b);
#pragma unroll
    for (int it = 0; it < 8; ++it) {
      int p   = tid + 256 * it;
      int row = p >> 4;
      int col = (p & 15) * 8;
      *reinterpret_cast<uint4*>(&W2s[row * HS + col]) = w2v[p];
    }
  }

  // load V fragment once (row j = 16w+m, cols 32ks+8quad+e) — reused both i
  const int j = 16 * w + m;
  const size_t base = (size_t)bn * 64;
  const float* vrow = V + (base + j) * 128;
  float v[4][8];
#pragma unroll
  for (int ks = 0; ks < 4; ++ks) {
    const int c0 = 32 * ks + 8 * quad;
    float4 v0 = *reinterpret_cast<const float4*>(vrow + c0);
    float4 v1 = *reinterpret_cast<const float4*>(vrow + c0 + 4);
    v[ks][0] = v0.x; v[ks][1] = v0.y; v[ks][2] = v0.z; v[ks][3] = v0.w;
    v[ks][4] = v1.x; v[ks][5] = v1.y; v[ks][6] = v1.z; v[ks][7] = v1.w;
  }

  bf16x8 frag[2][4];
#pragma unroll
  for (int ii = 0; ii < 2; ++ii) {
    const int i = i0 + ii;
    const bool dia = (j == i);
    const float* uprow = Up + (base + i) * 128;
    const float* dgrow = Dg + (base + i) * 128;

    float h[4][8];
    float s = 0.f, q = 0.f;
#pragma unroll
    for (int ks = 0; ks < 4; ++ks) {
      const int c0 = 32 * ks + 8 * quad;
      float4 u0 = *reinterpret_cast<const float4*>(uprow + c0);
      float4 u1 = *reinterpret_cast<const float4*>(uprow + c0 + 4);
      h[ks][0] = v[ks][0] + u0.x; h[ks][1] = v[ks][1] + u0.y;
      h[ks][2] = v[ks][2] + u0.z; h[ks][3] = v[ks][3] + u0.w;
      h[ks][4] = v[ks][4] + u1.x; h[ks][5] = v[ks][5] + u1.y;
      h[ks][6] = v[ks][6] + u1.z; h[ks][7] = v[ks][7] + u1.w;
      if (dia) {
        float4 d0 = *reinterpret_cast<const float4*>(dgrow + c0);
        float4 d1 = *reinterpret_cast<const float4*>(dgrow + c0 + 4);
        h[ks][0] += d0.x; h[ks][1] += d0.y; h[ks][2] += d0.z; h[ks][3] += d0.w;
        h[ks][4] += d1.x; h[ks][5] += d1.y; h[ks][6] += d1.z; h[ks][7] += d1.w;
      }
#pragma unroll
      for (int e = 0; e < 8; ++e) {
        s += h[ks][e];
        q += h[ks][e] * h[ks][e];
      }
    }
    // quad-reduce: lanes {m, m+16, m+32, m+48} together hold the full row
    s += __shfl_xor(s, 16, 64);
    s += __shfl_xor(s, 32, 64);
    q += __shfl_xor(q, 16, 64);
    q += __shfl_xor(q, 32, 64);
    const float mu   = s * (1.f / 128.f);
    const float var  = q * (1.f / 128.f) - mu * mu;
    const float rstd = rsqrtf(var + 1e-5f);

    // normalize -> bf16 B-fragment for this i
#pragma unroll
    for (int ks = 0; ks < 4; ++ks) {
      const int c0 = 32 * ks + 8 * quad;
      float4 g0  = *reinterpret_cast<const float4*>(gamma + c0);
      float4 g1  = *reinterpret_cast<const float4*>(gamma + c0 + 4);
      float4 be0 = *reinterpret_cast<const float4*>(beta + c0);
      float4 be1 = *reinterpret_cast<const float4*>(beta + c0 + 4);
      float gg[8] = {g0.x, g0.y, g0.z, g0.w, g1.x, g1.y, g1.z, g1.w};
      float bb[8] = {be0.x, be0.y, be0.z, be0.w, be1.x, be1.y, be1.z, be1.w};
      float r8[8];
#pragma unroll
      for (int e = 0; e < 8; ++e)
        r8[e] = fmaxf(fmaf((h[ks][e] - mu) * rstd, gg[e], bb[e]), 0.f);
      if (dia) {
        float4 bp0 = *reinterpret_cast<const float4*>(bias_p + c0);
        float4 bp1 = *reinterpret_cast<const float4*>(bias_p + c0 + 4);
        r8[0] += bp0.x; r8[1] += bp0.y; r8[2] += bp0.z; r8[3] += bp0.w;
        r8[4] += bp1.x; r8[5] += bp1.y; r8[6] += bp1.z; r8[7] += bp1.w;
      }
      bf16x8 f;
#pragma unroll
      for (int e = 0; e < 8; ++e) f[e] = (__bf16)r8[e];
      frag[ii][ks] = f;
    }
  }
  __syncthreads();

  // MFMA: A = W2s row d=16t+m (LDS, read once per t, feeds both i).
  // D[4*quad+rg -> d, m -> j]; rg contiguous in d => float4 stores.
  float* orow0 = out + ((size_t)(bn * 64 + i0) * 64 + j) * 128;
  float* orow1 = orow0 + 8192;   // i0+1
#pragma unroll
  for (int t = 0; t < 8; ++t) {
    f32x4v a0 = {0.f, 0.f, 0.f, 0.f};
    f32x4v a1 = {0.f, 0.f, 0.f, 0.f};
#pragma unroll
    for (int ks = 0; ks < 4; ++ks) {
      bf16x8 aw = *reinterpret_cast<const bf16x8*>(
          &W2s[(16 * t + m) * HS + 32 * ks + 8 * quad]);
      a0 = __builtin_amdgcn_mfma_f32_16x16x32_bf16(aw, frag[0][ks], a0, 0, 0, 0);
      a1 = __builtin_amdgcn_mfma_f32_16x16x32_bf16(aw, frag[1][ks], a1, 0, 0, 0);
    }
    const float4 b2v = *reinterpret_cast<const float4*>(b2 + 16 * t + 4 * quad);
    float4 o0, o1;
    o0.x = a0[0] + b2v.x; o0.y = a0[1] + b2v.y;
    o0.z = a0[2] + b2v.z; o0.w = a0[3] + b2v.w;
    o1.x = a1[0] + b2v.x; o1.y = a1[1] + b2v.y;
    o1.z = a1[2] + b2v.z; o1.w = a1[3] + b2v.w;
    *reinterpret_cast<float4*>(orow0 + 16 * t + 4 * quad) = o0;
    *reinterpret_cast<float4*>(orow1 + 16 * t + 4 * quad) = o1;
  }
}

extern "C" void kernel_launch(void* const* d_in, const int* in_sizes, int n_in,
                              void* d_out, int out_size, void* d_ws, size_t ws_size,
                              hipStream_t stream) {
  const float* x      = (const float*)d_in[0];
  const float* W1     = (const float*)d_in[1];
  const float* b1     = (const float*)d_in[2];
  const float* gamma  = (const float*)d_in[3];
  const float* beta   = (const float*)d_in[4];
  const float* bias_p = (const float*)d_in[5];
  const float* W2     = (const float*)d_in[6];
  const float* b2     = (const float*)d_in[7];

  float*  Up  = (float*)d_ws;
  float*  V   = Up + 2048 * 128;
  float*  Dg  = V + 2048 * 128;
  __bf16* W2b = (__bf16*)(Dg + 2048 * 128);

  k1_prep<<<192, 256, 0, stream>>>(x, W1, b1, W2, Up, V, Dg, W2b);
  k2_main<<<1024, 256, 0, stream>>>(Up, V, Dg, W2b, gamma, beta, bias_p, b2,
                                    (float*)d_out);
}

// Round 6
// 110.507 us; speedup vs baseline: 1.1708x; 1.0677x over previous
//
#include <hip/hip_runtime.h>

typedef __bf16 bf16x4 __attribute__((ext_vector_type(4)));
typedef __bf16 bf16x8 __attribute__((ext_vector_type(8)));
typedef float  f32x4v __attribute__((ext_vector_type(4)));

#define HS 136   // padded row stride in bf16 halfwords (272 B, 16B-aligned)

// ---------------------------------------------------------------------------
// inputs fp32, output fp32. h[bn,i,j,f] = Up[bn,i,f]+V[bn,j,f]+delta_ij*Dg[bn,i,f]
//   Up = x_i.W1b + mean.W1e + b1 ; V = x_j.W1c ; Dg = x_i.W1a + mean.W1d
// out = relu(LN_f(h))(+delta_ij*bias_p) @ W2^T + b2
// K1: split-bf16 MFMA (hi/lo, ~fp32-exact) -> Up/V/Dg fp32 ws + W2->bf16.
// K2: LN + diag + bf16 MFMA GEMM + direct fp32 store (R6-proven layouts).
// R12 NOTE (session ledger): this is the verified round-0 best (110.99 us).
//   R7 (W2 direct-from-L2), R9 (stats prekernel), R10/R11 (frag-direct
//   h-build) all regressed: the row-coalesced LDS h-build beats the
//   frag-direct gather (16 rows x 32B segments) by ~5 us, and extra
//   launches cost ~8-15 us. Remaining time = 2x46us harness poison fills
//   + ~11us output-write floor + ~8us k1/gaps => at the floor.
// ---------------------------------------------------------------------------

// K1: grid 192 = 32 bn x 6 chunks; chunk ch -> part pidx=ch>>1 (0=Dg,1=Up,2=V),
// f-tiles (4ch..4ch+3)&7 of that part.
__global__ __launch_bounds__(256) void k1_prep(
    const float* __restrict__ x, const float* __restrict__ W1,
    const float* __restrict__ b1, const float* __restrict__ W2,
    float* __restrict__ Up, float* __restrict__ V, float* __restrict__ Dg,
    __bf16* __restrict__ W2b)
{
  __shared__ __align__(16) __bf16 Xhi[64 * HS];
  __shared__ __align__(16) __bf16 Xlo[64 * HS];
  __shared__ float msum[128], pm[256], mw[128];

  const int tid  = threadIdx.x;
  const int bn   = blockIdx.x / 6;
  const int ch   = blockIdx.x % 6;
  const int lane = tid & 63;
  const int w    = tid >> 6;
  const int pidx = ch >> 1;

  if (tid < 128) msum[tid] = 0.f;
  __syncthreads();

  // stage x -> hi/lo bf16 LDS + fp32 column sums (atomic)
  {
    const float4* xv = reinterpret_cast<const float4*>(x + (size_t)bn * 8192);
    const int c = tid & 31;
    float4 ps = {0.f, 0.f, 0.f, 0.f};
#pragma unroll
    for (int it = 0; it < 8; ++it) {
      int p = tid + 256 * it;
      int r = p >> 5;
      float4 v = xv[p];
      ps.x += v.x; ps.y += v.y; ps.z += v.z; ps.w += v.w;
      bf16x4 hv, lv;
      hv[0] = (__bf16)v.x; lv[0] = (__bf16)(v.x - (float)hv[0]);
      hv[1] = (__bf16)v.y; lv[1] = (__bf16)(v.y - (float)hv[1]);
      hv[2] = (__bf16)v.z; lv[2] = (__bf16)(v.z - (float)hv[2]);
      hv[3] = (__bf16)v.w; lv[3] = (__bf16)(v.w - (float)hv[3]);
      *reinterpret_cast<bf16x4*>(&Xhi[r * HS + 4 * c]) = hv;
      *reinterpret_cast<bf16x4*>(&Xlo[r * HS + 4 * c]) = lv;
    }
    atomicAdd(&msum[4 * c + 0], ps.x);
    atomicAdd(&msum[4 * c + 1], ps.y);
    atomicAdd(&msum[4 * c + 2], ps.z);
    atomicAdd(&msum[4 * c + 3], ps.w);
  }

  // W2 fp32 -> bf16 ws (ch==4 blocks, identical writes: benign)
  if (ch == 4) {
    const float4* w2v = reinterpret_cast<const float4*>(W2);
#pragma unroll
    for (int it = 0; it < 16; ++it) {
      int p = tid + 256 * it;
      float4 v = w2v[p];
      bf16x4 hv;
      hv[0] = (__bf16)v.x; hv[1] = (__bf16)v.y;
      hv[2] = (__bf16)v.z; hv[3] = (__bf16)v.w;
      reinterpret_cast<bf16x4*>(W2b)[p] = hv;
    }
  }
  __syncthreads();

  // mean matvec (fp32): 2 threads per f, 64 MACs each; msum holds SUMS (x64)
  {
    const int f  = tid & 127;
    const int hh = tid >> 7;
    float acc = 0.f;
    if (pidx < 2) {
      const float4* wv4 = reinterpret_cast<const float4*>(
          W1 + (size_t)f * 640 + (pidx == 0 ? 384 : 512) + hh * 64);
#pragma unroll
      for (int kc = 0; kc < 16; ++kc) {
        float4 wv = wv4[kc];
        int k = hh * 64 + 4 * kc;
        acc += msum[k] * wv.x + msum[k + 1] * wv.y +
               msum[k + 2] * wv.z + msum[k + 3] * wv.w;
      }
    }
    pm[tid] = acc;
  }
  __syncthreads();
  if (tid < 128)
    mw[tid] = (pm[tid] + pm[tid + 128]) * (1.f / 64.f) +
              (pidx == 1 ? b1[tid] : 0.f);
  __syncthreads();

  // MFMA: wave w owns m-rows 16w..16w+15; 4 f-tiles x 4 ks x 3 (hi/lo) MFMAs
  const int m    = lane & 15;
  const int quad = lane >> 4;
  bf16x8 ahi[4], alo[4];
#pragma unroll
  for (int ks = 0; ks < 4; ++ks) {
    ahi[ks] = *reinterpret_cast<const bf16x8*>(&Xhi[(16 * w + m) * HS + 32 * ks + 8 * quad]);
    alo[ks] = *reinterpret_cast<const bf16x8*>(&Xlo[(16 * w + m) * HS + 32 * ks + 8 * quad]);
  }

  float* rout = (pidx == 0) ? Dg : (pidx == 1 ? Up : V);
#pragma unroll
  for (int tt = 0; tt < 4; ++tt) {
    const int fout = (((4 * ch + tt) & 7) * 16) + m;
    const float* wrow = W1 + (size_t)fout * 640 + pidx * 128;
    f32x4v a = {0.f, 0.f, 0.f, 0.f};
#pragma unroll
    for (int ks = 0; ks < 4; ++ks) {
      float4 w0 = *reinterpret_cast<const float4*>(wrow + 32 * ks + 8 * quad);
      float4 w1 = *reinterpret_cast<const float4*>(wrow + 32 * ks + 8 * quad + 4);
      bf16x8 bhi, blo;
      bhi[0] = (__bf16)w0.x; blo[0] = (__bf16)(w0.x - (float)bhi[0]);
      bhi[1] = (__bf16)w0.y; blo[1] = (__bf16)(w0.y - (float)bhi[1]);
      bhi[2] = (__bf16)w0.z; blo[2] = (__bf16)(w0.z - (float)bhi[2]);
      bhi[3] = (__bf16)w0.w; blo[3] = (__bf16)(w0.w - (float)bhi[3]);
      bhi[4] = (__bf16)w1.x; blo[4] = (__bf16)(w1.x - (float)bhi[4]);
      bhi[5] = (__bf16)w1.y; blo[5] = (__bf16)(w1.y - (float)bhi[5]);
      bhi[6] = (__bf16)w1.z; blo[6] = (__bf16)(w1.z - (float)bhi[6]);
      bhi[7] = (__bf16)w1.w; blo[7] = (__bf16)(w1.w - (float)bhi[7]);
      a = __builtin_amdgcn_mfma_f32_16x16x32_bf16(ahi[ks], bhi, a, 0, 0, 0);
      a = __builtin_amdgcn_mfma_f32_16x16x32_bf16(alo[ks], bhi, a, 0, 0, 0);
      a = __builtin_amdgcn_mfma_f32_16x16x32_bf16(ahi[ks], blo, a, 0, 0, 0);
    }
    const float addv = mw[fout];
#pragma unroll
    for (int rg = 0; rg < 4; ++rg) {
      int ii = 16 * w + 4 * quad + rg;
      rout[((size_t)bn * 64 + ii) * 128 + fout] = a[rg] + addv;
    }
  }
}

// K2: grid 2048 = (bn, i). LDS 52.2 KB -> 3 blocks/CU.
__global__ __launch_bounds__(256) void k2_main(
    const float* __restrict__ Up, const float* __restrict__ V,
    const float* __restrict__ Dg, const __bf16* __restrict__ W2b,
    const float* __restrict__ gamma, const float* __restrict__ beta,
    const float* __restrict__ bias_p, const float* __restrict__ b2,
    float* __restrict__ out)
{
  __shared__ __align__(16) __bf16 W2s[128 * HS];
  __shared__ __align__(16) __bf16 Hs[64 * HS];

  const int tid  = threadIdx.x;
  const int bid  = blockIdx.x;
  const int bn   = bid >> 6;
  const int i    = bid & 63;
  const int lane = tid & 63;
  const int w    = tid >> 6;

  // stage W2 bf16 into padded LDS
  {
    const uint4* w2v = reinterpret_cast<const uint4*>(W2b);
#pragma unroll
    for (int it = 0; it < 8; ++it) {
      int p   = tid + 256 * it;
      int row = p >> 4;
      int col = (p & 15) * 8;
      *reinterpret_cast<uint4*>(&W2s[row * HS + col]) = w2v[p];
    }
  }

  // h-build + LN; batch the 8 V-row loads first (independent -> MLP)
  {
    const int c    = lane & 31;
    const int half = lane >> 5;
    const size_t base = (size_t)bn * 64;
    const float4 up4 = reinterpret_cast<const float4*>(Up + (base + i) * 128)[c];
    const float4 dg4 = reinterpret_cast<const float4*>(Dg + (base + i) * 128)[c];
    const float4 g4  = reinterpret_cast<const float4*>(gamma)[c];
    const float4 be4 = reinterpret_cast<const float4*>(beta)[c];
    const float4 bp4 = reinterpret_cast<const float4*>(bias_p)[c];
    float4 v4s[8];
#pragma unroll
    for (int it = 0; it < 8; ++it) {
      int r = 8 * it + 2 * w + half;
      v4s[it] = reinterpret_cast<const float4*>(V + (base + r) * 128)[c];
    }
#pragma unroll
    for (int it = 0; it < 8; ++it) {
      int r = 8 * it + 2 * w + half;
      float4 v4 = v4s[it];
      float h0 = v4.x + up4.x, h1 = v4.y + up4.y;
      float h2 = v4.z + up4.z, h3 = v4.w + up4.w;
      if (r == i) { h0 += dg4.x; h1 += dg4.y; h2 += dg4.z; h3 += dg4.w; }
      float s = h0 + h1 + h2 + h3;
      float q = h0 * h0 + h1 * h1 + h2 * h2 + h3 * h3;
#pragma unroll
      for (int off = 16; off > 0; off >>= 1) {
        s += __shfl_xor(s, off, 32);
        q += __shfl_xor(q, off, 32);
      }
      float mu   = s * (1.f / 128.f);
      float var  = q * (1.f / 128.f) - mu * mu;
      float rstd = rsqrtf(var + 1e-5f);
      h0 = fmaxf(fmaf((h0 - mu) * rstd, g4.x, be4.x), 0.f);
      h1 = fmaxf(fmaf((h1 - mu) * rstd, g4.y, be4.y), 0.f);
      h2 = fmaxf(fmaf((h2 - mu) * rstd, g4.z, be4.z), 0.f);
      h3 = fmaxf(fmaf((h3 - mu) * rstd, g4.w, be4.w), 0.f);
      if (r == i) { h0 += bp4.x; h1 += bp4.y; h2 += bp4.z; h3 += bp4.w; }
      bf16x4 hv;
      hv[0] = (__bf16)h0; hv[1] = (__bf16)h1;
      hv[2] = (__bf16)h2; hv[3] = (__bf16)h3;
      *reinterpret_cast<bf16x4*>(&Hs[r * HS + 4 * c]) = hv;
    }
  }
  __syncthreads();

  // MFMA: out(64x128) = Hs x W2^T; A[m][k=32ks+8quad+j], B[n=m][k], D[4quad+rg][n]
  const int m    = lane & 15;
  const int quad = lane >> 4;
  bf16x8 af[4];
#pragma unroll
  for (int ks = 0; ks < 4; ++ks)
    af[ks] = *reinterpret_cast<const bf16x8*>(
        &Hs[(16 * w + m) * HS + 32 * ks + 8 * quad]);

  const size_t obase = (size_t)bid * 8192;
#pragma unroll
  for (int t = 0; t < 8; ++t) {
    f32x4v a = {0.f, 0.f, 0.f, 0.f};
#pragma unroll
    for (int ks = 0; ks < 4; ++ks) {
      bf16x8 bf = *reinterpret_cast<const bf16x8*>(
          &W2s[(16 * t + m) * HS + 32 * ks + 8 * quad]);
      a = __builtin_amdgcn_mfma_f32_16x16x32_bf16(af[ks], bf, a, 0, 0, 0);
    }
    const int d = 16 * t + m;
    const float b2v = b2[d];
#pragma unroll
    for (int rg = 0; rg < 4; ++rg) {
      int j = 16 * w + 4 * quad + rg;
      out[obase + (size_t)j * 128 + d] = a[rg] + b2v;
    }
  }
}

extern "C" void kernel_launch(void* const* d_in, const int* in_sizes, int n_in,
                              void* d_out, int out_size, void* d_ws, size_t ws_size,
                              hipStream_t stream) {
  const float* x      = (const float*)d_in[0];
  const float* W1     = (const float*)d_in[1];
  const float* b1     = (const float*)d_in[2];
  const float* gamma  = (const float*)d_in[3];
  const float* beta   = (const float*)d_in[4];
  const float* bias_p = (const float*)d_in[5];
  const float* W2     = (const float*)d_in[6];
  const float* b2     = (const float*)d_in[7];

  float*  Up  = (float*)d_ws;
  float*  V   = Up + 2048 * 128;
  float*  Dg  = V + 2048 * 128;
  __bf16* W2b = (__bf16*)(Dg + 2048 * 128);

  k1_prep<<<192, 256, 0, stream>>>(x, W1, b1, W2, Up, V, Dg, W2b);
  k2_main<<<2048, 256, 0, stream>>>(Up, V, Dg, W2b, gamma, beta, bias_p, b2,
                                    (float*)d_out);
}